// Round 1
// baseline (2905.397 us; speedup 1.0000x reference)
//
#include <hip/hip_runtime.h>
#include <stdint.h>

#define NN 100000
#define NE 1600000
#define DD 128
#define NTILES ((NN + 127) / 128)

typedef __bf16 bf16x8 __attribute__((ext_vector_type(8)));
typedef float f32x4 __attribute__((ext_vector_type(4)));

// round-to-nearest-even fp32 -> bf16, two at a time, packed into a uint
__device__ __forceinline__ unsigned int f2bf2(float a, float b) {
  union { float f; unsigned u; } x, y;
  x.f = a; y.f = b;
  unsigned ua = x.u + (0x7FFFu + ((x.u >> 16) & 1u));
  unsigned ub = y.u + (0x7FFFu + ((y.u >> 16) & 1u));
  return (ua >> 16) | (ub & 0xFFFF0000u);
}

// ---------------- edge scatter: neigh_sum[dst] += h[src]; deg[dst] += 1 -----
__global__ __launch_bounds__(256) void scatter_kernel(
    const float* __restrict__ h, const int* __restrict__ src,
    const int* __restrict__ dst, float* __restrict__ nsum,
    float* __restrict__ deg) {
  int gid = blockIdx.x * 256 + threadIdx.x;
  int e = gid >> 5;          // one edge per 32 lanes
  int lane = gid & 31;
  if (e >= NE) return;
  int s = src[e];
  int d = dst[e];
  const float4* hp = (const float4*)(h + (size_t)s * DD);
  float4 v = hp[lane];
  float* op = nsum + (size_t)d * DD + lane * 4;
  unsafeAtomicAdd(op + 0, v.x);
  unsafeAtomicAdd(op + 1, v.y);
  unsafeAtomicAdd(op + 2, v.z);
  unsafeAtomicAdd(op + 3, v.w);
  if (lane == 0) unsafeAtomicAdd(deg + d, 1.0f);
}

// ---------------- staging: fp32 row-major -> bf16 fragment-linear LDS -------
// chunk (row r, col-octet c8) -> buf[((rt*4+kc)<<6) + quad*16 + m], 16B each
template <bool SCALE>
__device__ __forceinline__ void stage_tile(const float* __restrict__ X,
                                           const float* __restrict__ deg,
                                           int row0, int nvalid,
                                           uint4* buf, int t) {
#pragma unroll
  for (int i = 0; i < 8; i++) {
    int id = t + (i << 8);     // 0..2047
    int r = id >> 4;           // 0..127
    int c8 = id & 15;          // 0..15
    int row = row0 + r;
    float4 v0 = {0.f, 0.f, 0.f, 0.f}, v1 = {0.f, 0.f, 0.f, 0.f};
    if (row < nvalid) {
      const float4* p = (const float4*)(X + (size_t)row * DD + (c8 << 3));
      v0 = p[0];
      v1 = p[1];
      if (SCALE) {
        float sc = 1.0f / fmaxf(deg[row], 1.0f);
        v0.x *= sc; v0.y *= sc; v0.z *= sc; v0.w *= sc;
        v1.x *= sc; v1.y *= sc; v1.z *= sc; v1.w *= sc;
      }
    }
    uint4 q;
    q.x = f2bf2(v0.x, v0.y);
    q.y = f2bf2(v0.z, v0.w);
    q.z = f2bf2(v1.x, v1.y);
    q.w = f2bf2(v1.z, v1.w);
    int rt = r >> 4, m = r & 15, kc = c8 >> 2, quad = c8 & 3;
    buf[(((rt << 2) + kc) << 6) + (quad << 4) + m] = q;
  }
}

__device__ __forceinline__ void compute_half(const uint4* sA, const uint4* sW,
                                             f32x4 acc[2][8], int wv, int lane) {
#pragma unroll
  for (int kc = 0; kc < 4; kc++) {
    bf16x8 b[8];
#pragma unroll
    for (int n = 0; n < 8; n++)
      b[n] = *(const bf16x8*)&sW[(((n << 2) + kc) << 6) + lane];
    bf16x8 a0 = *(const bf16x8*)&sA[((((wv * 2 + 0) << 2) + kc) << 6) + lane];
    bf16x8 a1 = *(const bf16x8*)&sA[((((wv * 2 + 1) << 2) + kc) << 6) + lane];
#pragma unroll
    for (int n = 0; n < 8; n++) {
      acc[0][n] = __builtin_amdgcn_mfma_f32_16x16x32_bf16(a0, b[n], acc[0][n], 0, 0, 0);
      acc[1][n] = __builtin_amdgcn_mfma_f32_16x16x32_bf16(a1, b[n], acc[1][n], 0, 0, 0);
    }
  }
}

// ---------------- fused: out = h@Ws^T + (nsum/deg)@Wn^T + b -----------------
__global__ __launch_bounds__(256) void gemm_kernel(
    const float* __restrict__ h, const float* __restrict__ nsum,
    const float* __restrict__ deg, const float* __restrict__ Wself,
    const float* __restrict__ Wneigh, const float* __restrict__ bias,
    float* __restrict__ out) {
  __shared__ uint4 sA[2048];   // 32 KB: 128-row A tile, bf16, frag-linear
  __shared__ uint4 sW[2048];   // 32 KB: 128x128 W, bf16, frag-linear
  int t = threadIdx.x;
  int wv = t >> 6;             // wave 0..3 -> row-tiles {2wv, 2wv+1}
  int lane = t & 63;

  for (int tile = blockIdx.x; tile < NTILES; tile += gridDim.x) {
    int row0 = tile * 128;
    f32x4 acc[2][8];
#pragma unroll
    for (int i = 0; i < 2; i++)
#pragma unroll
      for (int n = 0; n < 8; n++) acc[i][n] = f32x4{0.f, 0.f, 0.f, 0.f};

    // half 1: h @ Wself^T
    stage_tile<false>(h, nullptr, row0, NN, sA, t);
    stage_tile<false>(Wself, nullptr, 0, 128, sW, t);
    __syncthreads();
    compute_half(sA, sW, acc, wv, lane);
    __syncthreads();

    // half 2: (nsum/deg) @ Wneigh^T
    stage_tile<true>(nsum, deg, row0, NN, sA, t);
    stage_tile<false>(Wneigh, nullptr, 0, 128, sW, t);
    __syncthreads();
    compute_half(sA, sW, acc, wv, lane);

    // epilogue: + bias, store (C/D layout: col=lane&15, row=(lane>>4)*4+reg)
    int col = lane & 15, rq = lane >> 4;
    float bv[8];
#pragma unroll
    for (int n = 0; n < 8; n++) bv[n] = bias[n * 16 + col];
#pragma unroll
    for (int rt = 0; rt < 2; rt++) {
      int rb = row0 + (wv * 2 + rt) * 16 + rq * 4;
#pragma unroll
      for (int r = 0; r < 4; r++) {
        int row = rb + r;
        if (row < NN) {
          float* op = out + (size_t)row * DD + col;
#pragma unroll
          for (int n = 0; n < 8; n++) op[n * 16] = acc[rt][n][r] + bv[n];
        }
      }
    }
    __syncthreads();  // LDS reuse across grid-stride iterations
  }
}

extern "C" void kernel_launch(void* const* d_in, const int* in_sizes, int n_in,
                              void* d_out, int out_size, void* d_ws, size_t ws_size,
                              hipStream_t stream) {
  const float* h      = (const float*)d_in[0];
  const int*   src    = (const int*)d_in[1];
  const int*   dst    = (const int*)d_in[2];
  const float* Wself  = (const float*)d_in[3];
  const float* Wneigh = (const float*)d_in[4];
  const float* bias   = (const float*)d_in[5];
  float* out  = (float*)d_out;
  float* nsum = (float*)d_ws;                       // [NN*DD]
  float* deg  = nsum + (size_t)NN * DD;             // [NN]

  size_t zbytes = ((size_t)NN * DD + NN) * sizeof(float);
  hipMemsetAsync(d_ws, 0, zbytes, stream);

  scatter_kernel<<<(NE * 32) / 256, 256, 0, stream>>>(h, src, dst, nsum, deg);
  gemm_kernel<<<512, 256, 0, stream>>>(h, nsum, deg, Wself, Wneigh, bias, out);
}

// Round 2
// 427.671 us; speedup vs baseline: 6.7935x; 6.7935x over previous
//
#include <hip/hip_runtime.h>
#include <stdint.h>

#define NN 100000
#define NE 1600000
#define DD 128
#define NTILES ((NN + 127) / 128)
#define SCAN_TILE 256
#define NBLK ((NN + SCAN_TILE - 1) / SCAN_TILE)   // 391

typedef __bf16 bf16x8 __attribute__((ext_vector_type(8)));
typedef float f32x4 __attribute__((ext_vector_type(4)));

// round-to-nearest-even fp32 -> bf16, two at a time, packed into a uint
__device__ __forceinline__ unsigned int f2bf2(float a, float b) {
  union { float f; unsigned u; } x, y;
  x.f = a; y.f = b;
  unsigned ua = x.u + (0x7FFFu + ((x.u >> 16) & 1u));
  unsigned ub = y.u + (0x7FFFu + ((y.u >> 16) & 1u));
  return (ua >> 16) | (ub & 0xFFFF0000u);
}

// ---------------- 1. histogram of dst --------------------------------------
__global__ __launch_bounds__(256) void hist_kernel(const int* __restrict__ dst,
                                                   int* __restrict__ deg_i) {
  int gid = blockIdx.x * 256 + threadIdx.x;
  if (gid < NE) atomicAdd(&deg_i[dst[gid]], 1);
}

// ---------------- 2a. per-tile sums ----------------------------------------
__global__ __launch_bounds__(256) void blocksum_kernel(const int* __restrict__ deg_i,
                                                       int* __restrict__ bsum) {
  __shared__ int s[256];
  int t = threadIdx.x;
  int idx = blockIdx.x * 256 + t;
  s[t] = (idx < NN) ? deg_i[idx] : 0;
  __syncthreads();
  for (int d = 128; d > 0; d >>= 1) {
    if (t < d) s[t] += s[t + d];
    __syncthreads();
  }
  if (t == 0) bsum[blockIdx.x] = s[0];
}

// ---------------- 2b. scan tile sums (one block) ---------------------------
__global__ __launch_bounds__(512) void scanbsum_kernel(const int* __restrict__ bsum,
                                                       int* __restrict__ bsum_ex) {
  __shared__ int s[512];
  int t = threadIdx.x;
  int v = (t < NBLK) ? bsum[t] : 0;
  s[t] = v;
  __syncthreads();
  for (int d = 1; d < 512; d <<= 1) {
    int x = (t >= d) ? s[t - d] : 0;
    __syncthreads();
    s[t] += x;
    __syncthreads();
  }
  if (t < NBLK) bsum_ex[t] = s[t] - v;
}

// ---------------- 2c. full exclusive offsets + cursor ----------------------
__global__ __launch_bounds__(256) void offsets_kernel(const int* __restrict__ deg_i,
                                                      const int* __restrict__ bsum_ex,
                                                      int* __restrict__ offs,
                                                      int* __restrict__ cursor) {
  __shared__ int s[256];
  int t = threadIdx.x;
  int idx = blockIdx.x * 256 + t;
  int v = (idx < NN) ? deg_i[idx] : 0;
  s[t] = v;
  __syncthreads();
  for (int d = 1; d < 256; d <<= 1) {
    int x = (t >= d) ? s[t - d] : 0;
    __syncthreads();
    s[t] += x;
    __syncthreads();
  }
  int off = bsum_ex[blockIdx.x] + s[t] - v;
  if (idx < NN) {
    offs[idx] = off;
    cursor[idx] = off;
  } else if (idx == NN) {
    offs[NN] = NE;
  }
}

// ---------------- 3. CSR fill ----------------------------------------------
__global__ __launch_bounds__(256) void fill_kernel(const int* __restrict__ src,
                                                   const int* __restrict__ dst,
                                                   int* __restrict__ cursor,
                                                   int* __restrict__ csr) {
  int gid = blockIdx.x * 256 + threadIdx.x;
  if (gid < NE) {
    int pos = atomicAdd(&cursor[dst[gid]], 1);
    csr[pos] = src[gid];
  }
}

// ---------------- 4. gather-mean: hneigh[n] = mean(h[csr[offs..]]) ---------
__global__ __launch_bounds__(256) void gather_kernel(const float* __restrict__ h,
                                                     const int* __restrict__ offs,
                                                     const int* __restrict__ csr,
                                                     float* __restrict__ hneigh) {
  int wave = (blockIdx.x * 256 + threadIdx.x) >> 6;  // one node per wave
  int lane = threadIdx.x & 63;
  if (wave >= NN) return;
  int off0 = offs[wave], off1 = offs[wave + 1];
  const float2* hp = (const float2*)h;
  float2 acc = {0.f, 0.f};
  int j = off0;
  for (; j + 4 <= off1; j += 4) {
    int s0 = csr[j], s1 = csr[j + 1], s2 = csr[j + 2], s3 = csr[j + 3];
    float2 v0 = hp[(size_t)s0 * 64 + lane];
    float2 v1 = hp[(size_t)s1 * 64 + lane];
    float2 v2 = hp[(size_t)s2 * 64 + lane];
    float2 v3 = hp[(size_t)s3 * 64 + lane];
    acc.x += v0.x + v1.x + v2.x + v3.x;
    acc.y += v0.y + v1.y + v2.y + v3.y;
  }
  for (; j < off1; j++) {
    float2 v = hp[(size_t)csr[j] * 64 + lane];
    acc.x += v.x;
    acc.y += v.y;
  }
  int deg = off1 - off0;
  float sc = (deg > 0) ? (1.0f / (float)deg) : 0.0f;
  float2 r = {acc.x * sc, acc.y * sc};
  ((float2*)hneigh)[(size_t)wave * 64 + lane] = r;
}

// ---------------- staging: fp32 row-major -> bf16 fragment-linear LDS ------
__device__ __forceinline__ void stage_tile(const float* __restrict__ X,
                                           int row0, int nvalid,
                                           uint4* buf, int t) {
#pragma unroll
  for (int i = 0; i < 8; i++) {
    int id = t + (i << 8);     // 0..2047
    int r = id >> 4;           // 0..127
    int c8 = id & 15;          // 0..15
    int row = row0 + r;
    float4 v0 = {0.f, 0.f, 0.f, 0.f}, v1 = {0.f, 0.f, 0.f, 0.f};
    if (row < nvalid) {
      const float4* p = (const float4*)(X + (size_t)row * DD + (c8 << 3));
      v0 = p[0];
      v1 = p[1];
    }
    uint4 q;
    q.x = f2bf2(v0.x, v0.y);
    q.y = f2bf2(v0.z, v0.w);
    q.z = f2bf2(v1.x, v1.y);
    q.w = f2bf2(v1.z, v1.w);
    int rt = r >> 4, m = r & 15, kc = c8 >> 2, quad = c8 & 3;
    buf[(((rt << 2) + kc) << 6) + (quad << 4) + m] = q;
  }
}

__device__ __forceinline__ void compute_half(const uint4* sA, const uint4* sW,
                                             f32x4 acc[2][8], int wv, int lane) {
#pragma unroll
  for (int kc = 0; kc < 4; kc++) {
    bf16x8 b[8];
#pragma unroll
    for (int n = 0; n < 8; n++)
      b[n] = *(const bf16x8*)&sW[(((n << 2) + kc) << 6) + lane];
    bf16x8 a0 = *(const bf16x8*)&sA[((((wv * 2 + 0) << 2) + kc) << 6) + lane];
    bf16x8 a1 = *(const bf16x8*)&sA[((((wv * 2 + 1) << 2) + kc) << 6) + lane];
#pragma unroll
    for (int n = 0; n < 8; n++) {
      acc[0][n] = __builtin_amdgcn_mfma_f32_16x16x32_bf16(a0, b[n], acc[0][n], 0, 0, 0);
      acc[1][n] = __builtin_amdgcn_mfma_f32_16x16x32_bf16(a1, b[n], acc[1][n], 0, 0, 0);
    }
  }
}

// ---------------- 5. fused: out = h@Ws^T + hneigh@Wn^T + b -----------------
__global__ __launch_bounds__(256) void gemm_kernel(
    const float* __restrict__ h, const float* __restrict__ hneigh,
    const float* __restrict__ Wself, const float* __restrict__ Wneigh,
    const float* __restrict__ bias, float* __restrict__ out) {
  __shared__ uint4 sA[2048];   // 32 KB: 128-row A tile, bf16, frag-linear
  __shared__ uint4 sW[2048];   // 32 KB: 128x128 W, bf16, frag-linear
  int t = threadIdx.x;
  int wv = t >> 6;             // wave 0..3 -> row-tiles {2wv, 2wv+1}
  int lane = t & 63;

  for (int tile = blockIdx.x; tile < NTILES; tile += gridDim.x) {
    int row0 = tile * 128;
    f32x4 acc[2][8];
#pragma unroll
    for (int i = 0; i < 2; i++)
#pragma unroll
      for (int n = 0; n < 8; n++) acc[i][n] = f32x4{0.f, 0.f, 0.f, 0.f};

    // half 1: h @ Wself^T
    stage_tile(h, row0, NN, sA, t);
    stage_tile(Wself, 0, 128, sW, t);
    __syncthreads();
    compute_half(sA, sW, acc, wv, lane);
    __syncthreads();

    // half 2: hneigh @ Wneigh^T
    stage_tile(hneigh, row0, NN, sA, t);
    stage_tile(Wneigh, 0, 128, sW, t);
    __syncthreads();
    compute_half(sA, sW, acc, wv, lane);

    // epilogue: + bias, store (C/D layout: col=lane&15, row=(lane>>4)*4+reg)
    int col = lane & 15, rq = lane >> 4;
    float bv[8];
#pragma unroll
    for (int n = 0; n < 8; n++) bv[n] = bias[n * 16 + col];
#pragma unroll
    for (int rt = 0; rt < 2; rt++) {
      int rb = row0 + (wv * 2 + rt) * 16 + rq * 4;
#pragma unroll
      for (int r = 0; r < 4; r++) {
        int row = rb + r;
        if (row < NN) {
          float* op = out + (size_t)row * DD + col;
#pragma unroll
          for (int n = 0; n < 8; n++) op[n * 16] = acc[rt][n][r] + bv[n];
        }
      }
    }
    __syncthreads();  // LDS reuse across grid-stride iterations
  }
}

extern "C" void kernel_launch(void* const* d_in, const int* in_sizes, int n_in,
                              void* d_out, int out_size, void* d_ws, size_t ws_size,
                              hipStream_t stream) {
  const float* h      = (const float*)d_in[0];
  const int*   src    = (const int*)d_in[1];
  const int*   dst    = (const int*)d_in[2];
  const float* Wself  = (const float*)d_in[3];
  const float* Wneigh = (const float*)d_in[4];
  const float* bias   = (const float*)d_in[5];
  float* out = (float*)d_out;

  // workspace layout (bytes)
  char* ws = (char*)d_ws;
  float* hneigh  = (float*)ws;                                // 51,200,000
  int*   csr     = (int*)(ws + 51200000);                     //  6,400,000
  int*   deg_i   = (int*)(ws + 57600000);                     //    400,000
  int*   offs    = (int*)(ws + 58000000);                     //    400,016
  int*   cursor  = (int*)(ws + 58400016);                     //    400,000
  int*   bsum    = (int*)(ws + 58800016);                     //      1,564
  int*   bsum_ex = (int*)(ws + 58801600);                     //      1,564

  hipMemsetAsync(deg_i, 0, NN * sizeof(int), stream);

  int eblocks = (NE + 255) / 256;
  hist_kernel<<<eblocks, 256, 0, stream>>>(dst, deg_i);
  blocksum_kernel<<<NBLK, 256, 0, stream>>>(deg_i, bsum);
  scanbsum_kernel<<<1, 512, 0, stream>>>(bsum, bsum_ex);
  offsets_kernel<<<NBLK, 256, 0, stream>>>(deg_i, bsum_ex, offs, cursor);
  fill_kernel<<<eblocks, 256, 0, stream>>>(src, dst, cursor, csr);
  gather_kernel<<<(NN * 64 + 255) / 256, 256, 0, stream>>>(h, offs, csr, hneigh);
  gemm_kernel<<<512, 256, 0, stream>>>(h, hneigh, Wself, Wneigh, bias, out);
}

// Round 3
// 378.748 us; speedup vs baseline: 7.6711x; 1.1292x over previous
//
#include <hip/hip_runtime.h>
#include <stdint.h>

#define NN 100000
#define NE 1600000
#define DD 128
#define NTILES ((NN + 127) / 128)
#define NBLK ((NN + 255) / 256)   // 391
#define NPART 8
#define PSIZE (NN / NPART)        // 12500

typedef __bf16 bf16x8 __attribute__((ext_vector_type(8)));
typedef float f32x4 __attribute__((ext_vector_type(4)));

// round-to-nearest-even fp32 -> bf16, two at a time, packed into a uint
__device__ __forceinline__ unsigned int f2bf2(float a, float b) {
  union { float f; unsigned u; } x, y;
  x.f = a; y.f = b;
  unsigned ua = x.u + (0x7FFFu + ((x.u >> 16) & 1u));
  unsigned ub = y.u + (0x7FFFu + ((y.u >> 16) & 1u));
  return (ua >> 16) | (ub & 0xFFFF0000u);
}

// ---------------- 0a. h (fp32) -> hbf (bf16), 8 elems/thread ----------------
__global__ __launch_bounds__(256) void convert_h_kernel(const float4* __restrict__ hp,
                                                        uint4* __restrict__ hbf) {
  int gid = blockIdx.x * 256 + threadIdx.x;   // exactly NN*DD/8 = 1.6M threads
  float4 a = hp[2 * gid], b = hp[2 * gid + 1];
  uint4 q;
  q.x = f2bf2(a.x, a.y); q.y = f2bf2(a.z, a.w);
  q.z = f2bf2(b.x, b.y); q.w = f2bf2(b.z, b.w);
  hbf[gid] = q;
}

// ---------------- 0b. Wself,Wneigh (fp32) -> wbf (bf16, concat) -------------
__global__ __launch_bounds__(256) void convert_w_kernel(const float4* __restrict__ ws,
                                                        const float4* __restrict__ wn,
                                                        uint4* __restrict__ wbf) {
  int gid = blockIdx.x * 256 + threadIdx.x;   // 4096 threads
  const float4* p = (gid < 2048) ? ws : wn;
  int k = (gid < 2048) ? gid : gid - 2048;
  float4 a = p[2 * k], b = p[2 * k + 1];
  uint4 q;
  q.x = f2bf2(a.x, a.y); q.y = f2bf2(a.z, a.w);
  q.z = f2bf2(b.x, b.y); q.w = f2bf2(b.z, b.w);
  wbf[gid] = q;
}

// ---------------- 1. XCD-partitioned histogram of dst -----------------------
__global__ __launch_bounds__(256) void hist_kernel(const int* __restrict__ dst,
                                                   int* __restrict__ deg_i) {
  int p = blockIdx.x & (NPART - 1);          // partition == XCD (round-robin)
  int g = blockIdx.x >> 3;
  int nblk = gridDim.x >> 3;
  int lo = p * PSIZE, hi = lo + PSIZE;
  for (int e = g * 256 + threadIdx.x; e < NE; e += nblk * 256) {
    int d = dst[e];
    if (d >= lo && d < hi) atomicAdd(&deg_i[d], 1);
  }
}

// ---------------- 2a. per-tile sums -----------------------------------------
__global__ __launch_bounds__(256) void blocksum_kernel(const int* __restrict__ deg_i,
                                                       int* __restrict__ bsum) {
  __shared__ int s[256];
  int t = threadIdx.x;
  int idx = blockIdx.x * 256 + t;
  s[t] = (idx < NN) ? deg_i[idx] : 0;
  __syncthreads();
  for (int d = 128; d > 0; d >>= 1) {
    if (t < d) s[t] += s[t + d];
    __syncthreads();
  }
  if (t == 0) bsum[blockIdx.x] = s[0];
}

// ---------------- 2b. scan tile sums (one block) ----------------------------
__global__ __launch_bounds__(512) void scanbsum_kernel(const int* __restrict__ bsum,
                                                       int* __restrict__ bsum_ex) {
  __shared__ int s[512];
  int t = threadIdx.x;
  int v = (t < NBLK) ? bsum[t] : 0;
  s[t] = v;
  __syncthreads();
  for (int d = 1; d < 512; d <<= 1) {
    int x = (t >= d) ? s[t - d] : 0;
    __syncthreads();
    s[t] += x;
    __syncthreads();
  }
  if (t < NBLK) bsum_ex[t] = s[t] - v;
}

// ---------------- 2c. exclusive offsets -> cursor ---------------------------
__global__ __launch_bounds__(256) void offsets_kernel(const int* __restrict__ deg_i,
                                                      const int* __restrict__ bsum_ex,
                                                      int* __restrict__ cursor) {
  __shared__ int s[256];
  int t = threadIdx.x;
  int idx = blockIdx.x * 256 + t;
  int v = (idx < NN) ? deg_i[idx] : 0;
  s[t] = v;
  __syncthreads();
  for (int d = 1; d < 256; d <<= 1) {
    int x = (t >= d) ? s[t - d] : 0;
    __syncthreads();
    s[t] += x;
    __syncthreads();
  }
  if (idx < NN) cursor[idx] = bsum_ex[blockIdx.x] + s[t] - v;
}

// ---------------- 3. XCD-partitioned CSR fill -------------------------------
// after this kernel: cursor[d] == exclusive_offs[d+1]
__global__ __launch_bounds__(256) void fill_kernel(const int* __restrict__ src,
                                                   const int* __restrict__ dst,
                                                   int* __restrict__ cursor,
                                                   int* __restrict__ csr) {
  int p = blockIdx.x & (NPART - 1);
  int g = blockIdx.x >> 3;
  int nblk = gridDim.x >> 3;
  int lo = p * PSIZE, hi = lo + PSIZE;
  for (int e = g * 256 + threadIdx.x; e < NE; e += nblk * 256) {
    int d = dst[e];
    if (d >= lo && d < hi) {
      int pos = atomicAdd(&cursor[d], 1);
      csr[pos] = src[e];
    }
  }
}

// ---------------- 4. gather-mean over bf16 h --------------------------------
__global__ __launch_bounds__(256) void gather_kernel(const unsigned* __restrict__ hbf,
                                                     const int* __restrict__ cursor,
                                                     const int* __restrict__ csr,
                                                     unsigned* __restrict__ hneighbf) {
  int wave = (blockIdx.x * 256 + threadIdx.x) >> 6;  // one node per wave
  int lane = threadIdx.x & 63;
  if (wave >= NN) return;
  int off0 = (wave == 0) ? 0 : cursor[wave - 1];
  int off1 = cursor[wave];
  float ax = 0.f, ay = 0.f;
  int j = off0;
  for (; j + 4 <= off1; j += 4) {
    int s0 = csr[j], s1 = csr[j + 1], s2 = csr[j + 2], s3 = csr[j + 3];
    unsigned u0 = hbf[(size_t)s0 * 64 + lane];
    unsigned u1 = hbf[(size_t)s1 * 64 + lane];
    unsigned u2 = hbf[(size_t)s2 * 64 + lane];
    unsigned u3 = hbf[(size_t)s3 * 64 + lane];
    union { unsigned u; float f; } c;
    c.u = u0 << 16; ax += c.f; c.u = u0 & 0xFFFF0000u; ay += c.f;
    c.u = u1 << 16; ax += c.f; c.u = u1 & 0xFFFF0000u; ay += c.f;
    c.u = u2 << 16; ax += c.f; c.u = u2 & 0xFFFF0000u; ay += c.f;
    c.u = u3 << 16; ax += c.f; c.u = u3 & 0xFFFF0000u; ay += c.f;
  }
  for (; j < off1; j++) {
    unsigned u = hbf[(size_t)csr[j] * 64 + lane];
    union { unsigned u; float f; } c;
    c.u = u << 16; ax += c.f; c.u = u & 0xFFFF0000u; ay += c.f;
  }
  int deg = off1 - off0;
  float sc = (deg > 0) ? (1.0f / (float)deg) : 0.0f;
  hneighbf[(size_t)wave * 64 + lane] = f2bf2(ax * sc, ay * sc);
}

// ---------------- staging: bf16 row-major -> fragment-linear LDS (copy) -----
__device__ __forceinline__ void stage_bf(const uint4* __restrict__ X,
                                         int row0, int nvalid,
                                         uint4* buf, int t) {
#pragma unroll
  for (int i = 0; i < 8; i++) {
    int d = t + (i << 8);                 // dest chunk 0..2047
    int rt = d >> 8, kc = (d >> 6) & 3, quad = (d >> 4) & 3, m = d & 15;
    int r = rt * 16 + m, c8 = kc * 4 + quad;
    int row = row0 + r;
    uint4 q = {0u, 0u, 0u, 0u};
    if (row < nvalid) q = X[(size_t)row * 16 + c8];   // 16 chunks per bf16 row
    buf[d] = q;
  }
}

__device__ __forceinline__ void compute_half(const uint4* sA, const uint4* sW,
                                             f32x4 acc[2][8], int wv, int lane) {
#pragma unroll
  for (int kc = 0; kc < 4; kc++) {
    bf16x8 b[8];
#pragma unroll
    for (int n = 0; n < 8; n++)
      b[n] = *(const bf16x8*)&sW[(((n << 2) + kc) << 6) + lane];
    bf16x8 a0 = *(const bf16x8*)&sA[((((wv * 2 + 0) << 2) + kc) << 6) + lane];
    bf16x8 a1 = *(const bf16x8*)&sA[((((wv * 2 + 1) << 2) + kc) << 6) + lane];
#pragma unroll
    for (int n = 0; n < 8; n++) {
      acc[0][n] = __builtin_amdgcn_mfma_f32_16x16x32_bf16(a0, b[n], acc[0][n], 0, 0, 0);
      acc[1][n] = __builtin_amdgcn_mfma_f32_16x16x32_bf16(a1, b[n], acc[1][n], 0, 0, 0);
    }
  }
}

// ---------------- 5. fused: out = h@Ws^T + hneigh@Wn^T + b ------------------
__global__ __launch_bounds__(256) void gemm_kernel(
    const uint4* __restrict__ hbf, const uint4* __restrict__ hneighbf,
    const uint4* __restrict__ wbf, const float* __restrict__ bias,
    float* __restrict__ out) {
  __shared__ uint4 sA[2048];   // 32 KB
  __shared__ uint4 sW[2048];   // 32 KB
  int t = threadIdx.x;
  int wv = t >> 6;
  int lane = t & 63;

  for (int tile = blockIdx.x; tile < NTILES; tile += gridDim.x) {
    int row0 = tile * 128;
    f32x4 acc[2][8];
#pragma unroll
    for (int i = 0; i < 2; i++)
#pragma unroll
      for (int n = 0; n < 8; n++) acc[i][n] = f32x4{0.f, 0.f, 0.f, 0.f};

    // half 1: h @ Wself^T
    stage_bf(hbf, row0, NN, sA, t);
    stage_bf(wbf, 0, 128, sW, t);
    __syncthreads();
    compute_half(sA, sW, acc, wv, lane);
    __syncthreads();

    // half 2: hneigh @ Wneigh^T
    stage_bf(hneighbf, row0, NN, sA, t);
    stage_bf(wbf + 2048, 0, 128, sW, t);
    __syncthreads();
    compute_half(sA, sW, acc, wv, lane);

    // epilogue: + bias (C/D layout: col=lane&15, row=(lane>>4)*4+reg)
    int col = lane & 15, rq = lane >> 4;
    float bv[8];
#pragma unroll
    for (int n = 0; n < 8; n++) bv[n] = bias[n * 16 + col];
#pragma unroll
    for (int rt = 0; rt < 2; rt++) {
      int rb = row0 + (wv * 2 + rt) * 16 + rq * 4;
#pragma unroll
      for (int r = 0; r < 4; r++) {
        int row = rb + r;
        if (row < NN) {
          float* op = out + (size_t)row * DD + col;
#pragma unroll
          for (int n = 0; n < 8; n++) op[n * 16] = acc[rt][n][r] + bv[n];
        }
      }
    }
    __syncthreads();
  }
}

extern "C" void kernel_launch(void* const* d_in, const int* in_sizes, int n_in,
                              void* d_out, int out_size, void* d_ws, size_t ws_size,
                              hipStream_t stream) {
  const float* h      = (const float*)d_in[0];
  const int*   src    = (const int*)d_in[1];
  const int*   dst    = (const int*)d_in[2];
  const float* Wself  = (const float*)d_in[3];
  const float* Wneigh = (const float*)d_in[4];
  const float* bias   = (const float*)d_in[5];
  float* out = (float*)d_out;

  // workspace layout (bytes), total ~58.47 MB
  char* ws = (char*)d_ws;
  unsigned* hbf      = (unsigned*)ws;                     // 25,600,000
  unsigned* hneighbf = (unsigned*)(ws + 25600000);        // 25,600,000
  int*      csr      = (int*)(ws + 51200000);             //  6,400,000
  unsigned* wbf      = (unsigned*)(ws + 57600000);        //     65,536
  int*      deg_i    = (int*)(ws + 57665536);             //    400,000
  int*      cursor   = (int*)(ws + 58065536);             //    400,000
  int*      bsum     = (int*)(ws + 58465536);             //      1,564
  int*      bsum_ex  = (int*)(ws + 58467104);             //      1,564

  hipMemsetAsync(deg_i, 0, NN * sizeof(int), stream);

  convert_h_kernel<<<6250, 256, 0, stream>>>((const float4*)h, (uint4*)hbf);
  convert_w_kernel<<<16, 256, 0, stream>>>((const float4*)Wself, (const float4*)Wneigh,
                                           (uint4*)wbf);
  hist_kernel<<<512, 256, 0, stream>>>(dst, deg_i);
  blocksum_kernel<<<NBLK, 256, 0, stream>>>(deg_i, bsum);
  scanbsum_kernel<<<1, 512, 0, stream>>>(bsum, bsum_ex);
  offsets_kernel<<<NBLK, 256, 0, stream>>>(deg_i, bsum_ex, cursor);
  fill_kernel<<<512, 256, 0, stream>>>(src, dst, cursor, csr);
  gather_kernel<<<25000, 256, 0, stream>>>(hbf, cursor, csr, hneighbf);
  gemm_kernel<<<512, 256, 0, stream>>>((const uint4*)hbf, (const uint4*)hneighbf,
                                       (const uint4*)wbf, bias, out);
}

// Round 4
// 270.481 us; speedup vs baseline: 10.7416x; 1.4003x over previous
//
#include <hip/hip_runtime.h>
#include <stdint.h>

#define NN 100000
#define NE 1600000
#define DD 128
#define NTILES ((NN + 127) / 128)
#define NB 256                     // phase-A blocks
#define CHUNK (NE / NB)            // 6250
#define NBUCK ((NN + 255) / 256)   // 391 coarse buckets (dst>>8)
#define GH_N (NBUCK * NB)          // 100,096
#define GH_BLK (GH_N / 256)        // 391 scan blocks (exact)

typedef __bf16 bf16x8 __attribute__((ext_vector_type(8)));
typedef float f32x4 __attribute__((ext_vector_type(4)));

// round-to-nearest-even fp32 -> bf16, two at a time, packed into a uint
__device__ __forceinline__ unsigned int f2bf2(float a, float b) {
  union { float f; unsigned u; } x, y;
  x.f = a; y.f = b;
  unsigned ua = x.u + (0x7FFFu + ((x.u >> 16) & 1u));
  unsigned ub = y.u + (0x7FFFu + ((y.u >> 16) & 1u));
  return (ua >> 16) | (ub & 0xFFFF0000u);
}

// ---------------- 0a. h (fp32) -> hbf (bf16) --------------------------------
__global__ __launch_bounds__(256) void convert_h_kernel(const float4* __restrict__ hp,
                                                        uint4* __restrict__ hbf) {
  int gid = blockIdx.x * 256 + threadIdx.x;   // NN*DD/8 = 1.6M threads
  float4 a = hp[2 * gid], b = hp[2 * gid + 1];
  uint4 q;
  q.x = f2bf2(a.x, a.y); q.y = f2bf2(a.z, a.w);
  q.z = f2bf2(b.x, b.y); q.w = f2bf2(b.z, b.w);
  hbf[gid] = q;
}

// ---------------- 0b. Wself,Wneigh (fp32) -> wbf (bf16, concat) -------------
__global__ __launch_bounds__(256) void convert_w_kernel(const float4* __restrict__ ws,
                                                        const float4* __restrict__ wn,
                                                        uint4* __restrict__ wbf) {
  int gid = blockIdx.x * 256 + threadIdx.x;   // 4096 threads
  const float4* p = (gid < 2048) ? ws : wn;
  int k = (gid < 2048) ? gid : gid - 2048;
  float4 a = p[2 * k], b = p[2 * k + 1];
  uint4 q;
  q.x = f2bf2(a.x, a.y); q.y = f2bf2(a.z, a.w);
  q.z = f2bf2(b.x, b.y); q.w = f2bf2(b.z, b.w);
  wbf[gid] = q;
}

// ---------------- A1. coarse histogram (LDS atomics only) -------------------
__global__ __launch_bounds__(256) void coarse_hist_kernel(const int* __restrict__ dst,
                                                          int* __restrict__ gh) {
  __shared__ int lh[NBUCK];
  int t = threadIdx.x, b = blockIdx.x;
  for (int i = t; i < NBUCK; i += 256) lh[i] = 0;
  __syncthreads();
  int e0 = b * CHUNK;
  for (int e = e0 + t; e < e0 + CHUNK; e += 256)
    atomicAdd(&lh[dst[e] >> 8], 1);
  __syncthreads();
  for (int i = t; i < NBUCK; i += 256) gh[i * NB + b] = lh[i];
}

// ---------------- A2. hierarchical exclusive scan of gh ---------------------
__global__ __launch_bounds__(256) void blocksum_kernel(const int* __restrict__ gh,
                                                       int* __restrict__ bsum) {
  __shared__ int s[256];
  int t = threadIdx.x;
  s[t] = gh[blockIdx.x * 256 + t];
  __syncthreads();
  for (int d = 128; d > 0; d >>= 1) {
    if (t < d) s[t] += s[t + d];
    __syncthreads();
  }
  if (t == 0) bsum[blockIdx.x] = s[0];
}

__global__ __launch_bounds__(512) void scanbsum_kernel(const int* __restrict__ bsum,
                                                       int* __restrict__ bsum_ex) {
  __shared__ int s[512];
  int t = threadIdx.x;
  int v = (t < GH_BLK) ? bsum[t] : 0;
  s[t] = v;
  __syncthreads();
  for (int d = 1; d < 512; d <<= 1) {
    int x = (t >= d) ? s[t - d] : 0;
    __syncthreads();
    s[t] += x;
    __syncthreads();
  }
  if (t < GH_BLK) bsum_ex[t] = s[t] - v;
}

__global__ __launch_bounds__(256) void scanfull_kernel(const int* __restrict__ gh,
                                                       const int* __restrict__ bsum_ex,
                                                       int* __restrict__ gsc) {
  __shared__ int s[256];
  int t = threadIdx.x;
  int idx = blockIdx.x * 256 + t;
  int v = gh[idx];
  s[t] = v;
  __syncthreads();
  for (int d = 1; d < 256; d <<= 1) {
    int x = (t >= d) ? s[t - d] : 0;
    __syncthreads();
    s[t] += x;
    __syncthreads();
  }
  gsc[idx] = bsum_ex[blockIdx.x] + s[t] - v;
}

// ---------------- A3. coarse scatter into bucket-sorted ebuf ----------------
__global__ __launch_bounds__(256) void coarse_scatter_kernel(
    const int* __restrict__ src, const int* __restrict__ dst,
    const int* __restrict__ gsc, unsigned* __restrict__ ebuf) {
  __shared__ int cur[NBUCK];
  int t = threadIdx.x, b = blockIdx.x;
  for (int i = t; i < NBUCK; i += 256) cur[i] = gsc[i * NB + b];
  __syncthreads();
  int e0 = b * CHUNK;
  for (int e = e0 + t; e < e0 + CHUNK; e += 256) {
    int d = dst[e], s = src[e];
    int pos = atomicAdd(&cur[d >> 8], 1);
    ebuf[pos] = ((unsigned)(d & 255) << 24) | (unsigned)s;
  }
}

// ---------------- B. fine sort within bucket -> csr + offs ------------------
__global__ __launch_bounds__(256) void fine_sort_kernel(const unsigned* __restrict__ ebuf,
                                                        const int* __restrict__ gsc,
                                                        int* __restrict__ csr,
                                                        int* __restrict__ offs) {
  __shared__ int hist[256], scn[256], cur[256];
  int t = threadIdx.x, g = blockIdx.x;
  int base = gsc[g * NB];
  int end = (g == NBUCK - 1) ? NE : gsc[(g + 1) * NB];
  hist[t] = 0;
  __syncthreads();
  for (int j = base + t; j < end; j += 256)
    atomicAdd(&hist[ebuf[j] >> 24], 1);
  __syncthreads();
  int v = hist[t];
  scn[t] = v;
  __syncthreads();
  for (int d = 1; d < 256; d <<= 1) {
    int x = (t >= d) ? scn[t - d] : 0;
    __syncthreads();
    scn[t] += x;
    __syncthreads();
  }
  int excl = scn[t] - v;
  int node = g * 256 + t;
  if (node < NN) offs[node] = base + excl;
  if (node == NN - 1) offs[NN] = NE;
  cur[t] = excl;
  __syncthreads();
  for (int j = base + t; j < end; j += 256) {
    unsigned p = ebuf[j];
    int pos = atomicAdd(&cur[p >> 24], 1);
    csr[base + pos] = (int)(p & 0x00FFFFFFu);
  }
}

// ---------------- 4. gather-mean over bf16 h --------------------------------
__global__ __launch_bounds__(256) void gather_kernel(const unsigned* __restrict__ hbf,
                                                     const int* __restrict__ offs,
                                                     const int* __restrict__ csr,
                                                     unsigned* __restrict__ hneighbf) {
  int wave = (blockIdx.x * 256 + threadIdx.x) >> 6;  // one node per wave
  int lane = threadIdx.x & 63;
  if (wave >= NN) return;
  int off0 = offs[wave], off1 = offs[wave + 1];
  float ax = 0.f, ay = 0.f;
  int j = off0;
  for (; j + 4 <= off1; j += 4) {
    int s0 = csr[j], s1 = csr[j + 1], s2 = csr[j + 2], s3 = csr[j + 3];
    unsigned u0 = hbf[(size_t)s0 * 64 + lane];
    unsigned u1 = hbf[(size_t)s1 * 64 + lane];
    unsigned u2 = hbf[(size_t)s2 * 64 + lane];
    unsigned u3 = hbf[(size_t)s3 * 64 + lane];
    union { unsigned u; float f; } c;
    c.u = u0 << 16; ax += c.f; c.u = u0 & 0xFFFF0000u; ay += c.f;
    c.u = u1 << 16; ax += c.f; c.u = u1 & 0xFFFF0000u; ay += c.f;
    c.u = u2 << 16; ax += c.f; c.u = u2 & 0xFFFF0000u; ay += c.f;
    c.u = u3 << 16; ax += c.f; c.u = u3 & 0xFFFF0000u; ay += c.f;
  }
  for (; j < off1; j++) {
    unsigned u = hbf[(size_t)csr[j] * 64 + lane];
    union { unsigned u; float f; } c;
    c.u = u << 16; ax += c.f; c.u = u & 0xFFFF0000u; ay += c.f;
  }
  int deg = off1 - off0;
  float sc = (deg > 0) ? (1.0f / (float)deg) : 0.0f;
  hneighbf[(size_t)wave * 64 + lane] = f2bf2(ax * sc, ay * sc);
}

// ---------------- staging: bf16 row-major -> fragment-linear LDS ------------
__device__ __forceinline__ void stage_bf(const uint4* __restrict__ X,
                                         int row0, int nvalid,
                                         uint4* buf, int t) {
#pragma unroll
  for (int i = 0; i < 8; i++) {
    int d = t + (i << 8);                 // dest chunk 0..2047
    int rt = d >> 8, kc = (d >> 6) & 3, quad = (d >> 4) & 3, m = d & 15;
    int r = rt * 16 + m, c8 = kc * 4 + quad;
    int row = row0 + r;
    uint4 q = {0u, 0u, 0u, 0u};
    if (row < nvalid) q = X[(size_t)row * 16 + c8];
    buf[d] = q;
  }
}

__device__ __forceinline__ void compute_half(const uint4* sA, const uint4* sW,
                                             f32x4 acc[2][8], int wv, int lane) {
#pragma unroll
  for (int kc = 0; kc < 4; kc++) {
    bf16x8 b[8];
#pragma unroll
    for (int n = 0; n < 8; n++)
      b[n] = *(const bf16x8*)&sW[(((n << 2) + kc) << 6) + lane];
    bf16x8 a0 = *(const bf16x8*)&sA[((((wv * 2 + 0) << 2) + kc) << 6) + lane];
    bf16x8 a1 = *(const bf16x8*)&sA[((((wv * 2 + 1) << 2) + kc) << 6) + lane];
#pragma unroll
    for (int n = 0; n < 8; n++) {
      acc[0][n] = __builtin_amdgcn_mfma_f32_16x16x32_bf16(a0, b[n], acc[0][n], 0, 0, 0);
      acc[1][n] = __builtin_amdgcn_mfma_f32_16x16x32_bf16(a1, b[n], acc[1][n], 0, 0, 0);
    }
  }
}

// ---------------- 5. fused: out = h@Ws^T + hneigh@Wn^T + b ------------------
__global__ __launch_bounds__(256) void gemm_kernel(
    const uint4* __restrict__ hbf, const uint4* __restrict__ hneighbf,
    const uint4* __restrict__ wbf, const float* __restrict__ bias,
    float* __restrict__ out) {
  __shared__ uint4 sA[2048];
  __shared__ uint4 sW[2048];
  int t = threadIdx.x;
  int wv = t >> 6;
  int lane = t & 63;

  for (int tile = blockIdx.x; tile < NTILES; tile += gridDim.x) {
    int row0 = tile * 128;
    f32x4 acc[2][8];
#pragma unroll
    for (int i = 0; i < 2; i++)
#pragma unroll
      for (int n = 0; n < 8; n++) acc[i][n] = f32x4{0.f, 0.f, 0.f, 0.f};

    stage_bf(hbf, row0, NN, sA, t);
    stage_bf(wbf, 0, 128, sW, t);
    __syncthreads();
    compute_half(sA, sW, acc, wv, lane);
    __syncthreads();

    stage_bf(hneighbf, row0, NN, sA, t);
    stage_bf(wbf + 2048, 0, 128, sW, t);
    __syncthreads();
    compute_half(sA, sW, acc, wv, lane);

    int col = lane & 15, rq = lane >> 4;
    float bv[8];
#pragma unroll
    for (int n = 0; n < 8; n++) bv[n] = bias[n * 16 + col];
#pragma unroll
    for (int rt = 0; rt < 2; rt++) {
      int rb = row0 + (wv * 2 + rt) * 16 + rq * 4;
#pragma unroll
      for (int r = 0; r < 4; r++) {
        int row = rb + r;
        if (row < NN) {
          float* op = out + (size_t)row * DD + col;
#pragma unroll
          for (int n = 0; n < 8; n++) op[n * 16] = acc[rt][n][r] + bv[n];
        }
      }
    }
    __syncthreads();
  }
}

extern "C" void kernel_launch(void* const* d_in, const int* in_sizes, int n_in,
                              void* d_out, int out_size, void* d_ws, size_t ws_size,
                              hipStream_t stream) {
  const float* h      = (const float*)d_in[0];
  const int*   src    = (const int*)d_in[1];
  const int*   dst    = (const int*)d_in[2];
  const float* Wself  = (const float*)d_in[3];
  const float* Wneigh = (const float*)d_in[4];
  const float* bias   = (const float*)d_in[5];
  float* out = (float*)d_out;

  // workspace layout (bytes); ebuf/gh/gsc/bsum alias hneighbf's region
  // (dead until gather). Total footprint: 58,065,552 B.
  char* ws = (char*)d_ws;
  unsigned* hbf      = (unsigned*)ws;                     // 25,600,000
  unsigned* hneighbf = (unsigned*)(ws + 25600000);        // 25,600,000
  unsigned* ebuf     = (unsigned*)(ws + 25600000);        //  6,400,000 (alias)
  int*      gh       = (int*)(ws + 32000000);             //    400,384 (alias)
  int*      gsc      = (int*)(ws + 32400384);             //    400,384 (alias)
  int*      bsum     = (int*)(ws + 32800768);             //      1,568 (alias)
  int*      bsum_ex  = (int*)(ws + 32802336);             //      1,568 (alias)
  int*      csr      = (int*)(ws + 51200000);             //  6,400,000
  unsigned* wbf      = (unsigned*)(ws + 57600000);        //     65,536
  int*      offs     = (int*)(ws + 57665536);             //    400,016

  convert_h_kernel<<<6250, 256, 0, stream>>>((const float4*)h, (uint4*)hbf);
  convert_w_kernel<<<16, 256, 0, stream>>>((const float4*)Wself, (const float4*)Wneigh,
                                           (uint4*)wbf);
  coarse_hist_kernel<<<NB, 256, 0, stream>>>(dst, gh);
  blocksum_kernel<<<GH_BLK, 256, 0, stream>>>(gh, bsum);
  scanbsum_kernel<<<1, 512, 0, stream>>>(bsum, bsum_ex);
  scanfull_kernel<<<GH_BLK, 256, 0, stream>>>(gh, bsum_ex, gsc);
  coarse_scatter_kernel<<<NB, 256, 0, stream>>>(src, dst, gsc, ebuf);
  fine_sort_kernel<<<NBUCK, 256, 0, stream>>>(ebuf, gsc, csr, offs);
  gather_kernel<<<25000, 256, 0, stream>>>(hbf, offs, csr, hneighbf);
  gemm_kernel<<<512, 256, 0, stream>>>((const uint4*)hbf, (const uint4*)hneighbf,
                                       (const uint4*)wbf, bias, out);
}

// Round 5
// 258.702 us; speedup vs baseline: 11.2307x; 1.0455x over previous
//
#include <hip/hip_runtime.h>
#include <stdint.h>

#define NN 100000
#define NE 1600000
#define DD 128
#define NTILES ((NN + 127) / 128)
#define NB 256                     // phase-A blocks
#define CHUNK (NE / NB)            // 6250
#define NBUCK ((NN + 255) / 256)   // 391 coarse buckets (dst>>8)
#define GH_N (NBUCK * NB)          // 100,096
#define GH_BLK (GH_N / 256)        // 391 scan blocks (exact)

typedef __bf16 bf16x8 __attribute__((ext_vector_type(8)));
typedef float f32x4 __attribute__((ext_vector_type(4)));

// round-to-nearest-even fp32 -> bf16, two at a time, packed into a uint
__device__ __forceinline__ unsigned int f2bf2(float a, float b) {
  union { float f; unsigned u; } x, y;
  x.f = a; y.f = b;
  unsigned ua = x.u + (0x7FFFu + ((x.u >> 16) & 1u));
  unsigned ub = y.u + (0x7FFFu + ((y.u >> 16) & 1u));
  return (ua >> 16) | (ub & 0xFFFF0000u);
}

__device__ __forceinline__ void acc8(float* a, uint4 u) {
  union { unsigned u; float f; } c;
  c.u = u.x << 16;         a[0] += c.f;
  c.u = u.x & 0xFFFF0000u; a[1] += c.f;
  c.u = u.y << 16;         a[2] += c.f;
  c.u = u.y & 0xFFFF0000u; a[3] += c.f;
  c.u = u.z << 16;         a[4] += c.f;
  c.u = u.z & 0xFFFF0000u; a[5] += c.f;
  c.u = u.w << 16;         a[6] += c.f;
  c.u = u.w & 0xFFFF0000u; a[7] += c.f;
}

// ---------------- 0a. h (fp32) -> hbf (bf16) --------------------------------
__global__ __launch_bounds__(256) void convert_h_kernel(const float4* __restrict__ hp,
                                                        uint4* __restrict__ hbf) {
  int gid = blockIdx.x * 256 + threadIdx.x;   // NN*DD/8 = 1.6M threads
  float4 a = hp[2 * gid], b = hp[2 * gid + 1];
  uint4 q;
  q.x = f2bf2(a.x, a.y); q.y = f2bf2(a.z, a.w);
  q.z = f2bf2(b.x, b.y); q.w = f2bf2(b.z, b.w);
  hbf[gid] = q;
}

// ---------------- 0b. Wself,Wneigh (fp32) -> wbf (bf16, concat) -------------
__global__ __launch_bounds__(256) void convert_w_kernel(const float4* __restrict__ ws,
                                                        const float4* __restrict__ wn,
                                                        uint4* __restrict__ wbf) {
  int gid = blockIdx.x * 256 + threadIdx.x;   // 4096 threads
  const float4* p = (gid < 2048) ? ws : wn;
  int k = (gid < 2048) ? gid : gid - 2048;
  float4 a = p[2 * k], b = p[2 * k + 1];
  uint4 q;
  q.x = f2bf2(a.x, a.y); q.y = f2bf2(a.z, a.w);
  q.z = f2bf2(b.x, b.y); q.w = f2bf2(b.z, b.w);
  wbf[gid] = q;
}

// ---------------- A1. coarse histogram (LDS atomics only) -------------------
__global__ __launch_bounds__(256) void coarse_hist_kernel(const int* __restrict__ dst,
                                                          int* __restrict__ gh) {
  __shared__ int lh[NBUCK];
  int t = threadIdx.x, b = blockIdx.x;
  for (int i = t; i < NBUCK; i += 256) lh[i] = 0;
  __syncthreads();
  int e0 = b * CHUNK;
  for (int e = e0 + t; e < e0 + CHUNK; e += 256)
    atomicAdd(&lh[dst[e] >> 8], 1);
  __syncthreads();
  for (int i = t; i < NBUCK; i += 256) gh[i * NB + b] = lh[i];
}

// ---------------- A2. hierarchical exclusive scan of gh ---------------------
__global__ __launch_bounds__(256) void blocksum_kernel(const int* __restrict__ gh,
                                                       int* __restrict__ bsum) {
  __shared__ int s[256];
  int t = threadIdx.x;
  s[t] = gh[blockIdx.x * 256 + t];
  __syncthreads();
  for (int d = 128; d > 0; d >>= 1) {
    if (t < d) s[t] += s[t + d];
    __syncthreads();
  }
  if (t == 0) bsum[blockIdx.x] = s[0];
}

__global__ __launch_bounds__(512) void scanbsum_kernel(const int* __restrict__ bsum,
                                                       int* __restrict__ bsum_ex) {
  __shared__ int s[512];
  int t = threadIdx.x;
  int v = (t < GH_BLK) ? bsum[t] : 0;
  s[t] = v;
  __syncthreads();
  for (int d = 1; d < 512; d <<= 1) {
    int x = (t >= d) ? s[t - d] : 0;
    __syncthreads();
    s[t] += x;
    __syncthreads();
  }
  if (t < GH_BLK) bsum_ex[t] = s[t] - v;
}

__global__ __launch_bounds__(256) void scanfull_kernel(const int* __restrict__ gh,
                                                       const int* __restrict__ bsum_ex,
                                                       int* __restrict__ gsc) {
  __shared__ int s[256];
  int t = threadIdx.x;
  int idx = blockIdx.x * 256 + t;
  int v = gh[idx];
  s[t] = v;
  __syncthreads();
  for (int d = 1; d < 256; d <<= 1) {
    int x = (t >= d) ? s[t - d] : 0;
    __syncthreads();
    s[t] += x;
    __syncthreads();
  }
  gsc[idx] = bsum_ex[blockIdx.x] + s[t] - v;
}

// ---------------- A3. coarse scatter into bucket-sorted ebuf ----------------
__global__ __launch_bounds__(256) void coarse_scatter_kernel(
    const int* __restrict__ src, const int* __restrict__ dst,
    const int* __restrict__ gsc, unsigned* __restrict__ ebuf) {
  __shared__ int cur[NBUCK];
  int t = threadIdx.x, b = blockIdx.x;
  for (int i = t; i < NBUCK; i += 256) cur[i] = gsc[i * NB + b];
  __syncthreads();
  int e0 = b * CHUNK;
  for (int e = e0 + t; e < e0 + CHUNK; e += 256) {
    int d = dst[e], s = src[e];
    int pos = atomicAdd(&cur[d >> 8], 1);
    ebuf[pos] = ((unsigned)(d & 255) << 24) | (unsigned)s;
  }
}

// ---------------- B. fine sort within bucket -> csr + offs ------------------
__global__ __launch_bounds__(256) void fine_sort_kernel(const unsigned* __restrict__ ebuf,
                                                        const int* __restrict__ gsc,
                                                        int* __restrict__ csr,
                                                        int* __restrict__ offs) {
  __shared__ int hist[256], scn[256], cur[256];
  int t = threadIdx.x, g = blockIdx.x;
  int base = gsc[g * NB];
  int end = (g == NBUCK - 1) ? NE : gsc[(g + 1) * NB];
  hist[t] = 0;
  __syncthreads();
  for (int j = base + t; j < end; j += 256)
    atomicAdd(&hist[ebuf[j] >> 24], 1);
  __syncthreads();
  int v = hist[t];
  scn[t] = v;
  __syncthreads();
  for (int d = 1; d < 256; d <<= 1) {
    int x = (t >= d) ? scn[t - d] : 0;
    __syncthreads();
    scn[t] += x;
    __syncthreads();
  }
  int excl = scn[t] - v;
  int node = g * 256 + t;
  if (node < NN) offs[node] = base + excl;
  if (node == NN - 1) offs[NN] = NE;
  cur[t] = excl;
  __syncthreads();
  for (int j = base + t; j < end; j += 256) {
    unsigned p = ebuf[j];
    int pos = atomicAdd(&cur[p >> 24], 1);
    csr[base + pos] = (int)(p & 0x00FFFFFFu);
  }
}

// ---------------- 4. gather-mean, one node per quarter-wave -----------------
// 16 lanes x uint4 = 256 B = one bf16 row; 4 rows per wave-load instruction.
__global__ __launch_bounds__(256) void gather_kernel(const uint4* __restrict__ hbf4,
                                                     const int* __restrict__ offs,
                                                     const int* __restrict__ csr,
                                                     uint4* __restrict__ hneighbf4) {
  int q = (blockIdx.x * 256 + threadIdx.x) >> 4;   // node id
  int l = threadIdx.x & 15;                        // chunk within row
  if (q >= NN) return;
  int off0 = offs[q], off1 = offs[q + 1];
  float a[8] = {0.f, 0.f, 0.f, 0.f, 0.f, 0.f, 0.f, 0.f};
  int j = off0;
  for (; j + 4 <= off1; j += 4) {
    int s0 = csr[j], s1 = csr[j + 1], s2 = csr[j + 2], s3 = csr[j + 3];
    uint4 u0 = hbf4[(size_t)s0 * 16 + l];
    uint4 u1 = hbf4[(size_t)s1 * 16 + l];
    uint4 u2 = hbf4[(size_t)s2 * 16 + l];
    uint4 u3 = hbf4[(size_t)s3 * 16 + l];
    acc8(a, u0); acc8(a, u1); acc8(a, u2); acc8(a, u3);
  }
  for (; j < off1; j++) {
    uint4 u = hbf4[(size_t)csr[j] * 16 + l];
    acc8(a, u);
  }
  int deg = off1 - off0;
  float sc = (deg > 0) ? (1.0f / (float)deg) : 0.0f;
  uint4 r;
  r.x = f2bf2(a[0] * sc, a[1] * sc);
  r.y = f2bf2(a[2] * sc, a[3] * sc);
  r.z = f2bf2(a[4] * sc, a[5] * sc);
  r.w = f2bf2(a[6] * sc, a[7] * sc);
  hneighbf4[(size_t)q * 16 + l] = r;
}

// ---------------- staging: bf16 row-major -> fragment-linear LDS ------------
__device__ __forceinline__ void stage_bf(const uint4* __restrict__ X,
                                         int row0, int nvalid,
                                         uint4* buf, int t) {
#pragma unroll
  for (int i = 0; i < 8; i++) {
    int d = t + (i << 8);                 // dest chunk 0..2047
    int rt = d >> 8, kc = (d >> 6) & 3, quad = (d >> 4) & 3, m = d & 15;
    int r = rt * 16 + m, c8 = kc * 4 + quad;
    int row = row0 + r;
    uint4 q = {0u, 0u, 0u, 0u};
    if (row < nvalid) q = X[(size_t)row * 16 + c8];
    buf[d] = q;
  }
}

__device__ __forceinline__ void compute_half(const uint4* sA, const uint4* sW,
                                             f32x4 acc[2][8], int wv, int lane) {
#pragma unroll
  for (int kc = 0; kc < 4; kc++) {
    bf16x8 b[8];
#pragma unroll
    for (int n = 0; n < 8; n++)
      b[n] = *(const bf16x8*)&sW[(((n << 2) + kc) << 6) + lane];
    bf16x8 a0 = *(const bf16x8*)&sA[((((wv * 2 + 0) << 2) + kc) << 6) + lane];
    bf16x8 a1 = *(const bf16x8*)&sA[((((wv * 2 + 1) << 2) + kc) << 6) + lane];
#pragma unroll
    for (int n = 0; n < 8; n++) {
      acc[0][n] = __builtin_amdgcn_mfma_f32_16x16x32_bf16(a0, b[n], acc[0][n], 0, 0, 0);
      acc[1][n] = __builtin_amdgcn_mfma_f32_16x16x32_bf16(a1, b[n], acc[1][n], 0, 0, 0);
    }
  }
}

// ---------------- 5. fused: out = h@Ws^T + hneigh@Wn^T + b ------------------
__global__ __launch_bounds__(256) void gemm_kernel(
    const uint4* __restrict__ hbf, const uint4* __restrict__ hneighbf,
    const uint4* __restrict__ wbf, const float* __restrict__ bias,
    float* __restrict__ out) {
  __shared__ uint4 sA[2048];
  __shared__ uint4 sW[2048];
  int t = threadIdx.x;
  int wv = t >> 6;
  int lane = t & 63;

  for (int tile = blockIdx.x; tile < NTILES; tile += gridDim.x) {
    int row0 = tile * 128;
    f32x4 acc[2][8];
#pragma unroll
    for (int i = 0; i < 2; i++)
#pragma unroll
      for (int n = 0; n < 8; n++) acc[i][n] = f32x4{0.f, 0.f, 0.f, 0.f};

    stage_bf(hbf, row0, NN, sA, t);
    stage_bf(wbf, 0, 128, sW, t);
    __syncthreads();
    compute_half(sA, sW, acc, wv, lane);
    __syncthreads();

    stage_bf(hneighbf, row0, NN, sA, t);
    stage_bf(wbf + 2048, 0, 128, sW, t);
    __syncthreads();
    compute_half(sA, sW, acc, wv, lane);

    int col = lane & 15, rq = lane >> 4;
    float bv[8];
#pragma unroll
    for (int n = 0; n < 8; n++) bv[n] = bias[n * 16 + col];
#pragma unroll
    for (int rt = 0; rt < 2; rt++) {
      int rb = row0 + (wv * 2 + rt) * 16 + rq * 4;
#pragma unroll
      for (int r = 0; r < 4; r++) {
        int row = rb + r;
        if (row < NN) {
          float* op = out + (size_t)row * DD + col;
#pragma unroll
          for (int n = 0; n < 8; n++) op[n * 16] = acc[rt][n][r] + bv[n];
        }
      }
    }
    __syncthreads();
  }
}

extern "C" void kernel_launch(void* const* d_in, const int* in_sizes, int n_in,
                              void* d_out, int out_size, void* d_ws, size_t ws_size,
                              hipStream_t stream) {
  const float* h      = (const float*)d_in[0];
  const int*   src    = (const int*)d_in[1];
  const int*   dst    = (const int*)d_in[2];
  const float* Wself  = (const float*)d_in[3];
  const float* Wneigh = (const float*)d_in[4];
  const float* bias   = (const float*)d_in[5];
  float* out = (float*)d_out;

  // workspace layout (bytes); ebuf/gh/gsc/bsum alias hneighbf's region
  // (dead until gather). Total footprint: 58,065,552 B.
  char* ws = (char*)d_ws;
  unsigned* hbf      = (unsigned*)ws;                     // 25,600,000
  unsigned* hneighbf = (unsigned*)(ws + 25600000);        // 25,600,000
  unsigned* ebuf     = (unsigned*)(ws + 25600000);        //  6,400,000 (alias)
  int*      gh       = (int*)(ws + 32000000);             //    400,384 (alias)
  int*      gsc      = (int*)(ws + 32400384);             //    400,384 (alias)
  int*      bsum     = (int*)(ws + 32800768);             //      1,568 (alias)
  int*      bsum_ex  = (int*)(ws + 32802336);             //      1,568 (alias)
  int*      csr      = (int*)(ws + 51200000);             //  6,400,000
  unsigned* wbf      = (unsigned*)(ws + 57600000);        //     65,536
  int*      offs     = (int*)(ws + 57665536);             //    400,016

  convert_h_kernel<<<6250, 256, 0, stream>>>((const float4*)h, (uint4*)hbf);
  convert_w_kernel<<<16, 256, 0, stream>>>((const float4*)Wself, (const float4*)Wneigh,
                                           (uint4*)wbf);
  coarse_hist_kernel<<<NB, 256, 0, stream>>>(dst, gh);
  blocksum_kernel<<<GH_BLK, 256, 0, stream>>>(gh, bsum);
  scanbsum_kernel<<<1, 512, 0, stream>>>(bsum, bsum_ex);
  scanfull_kernel<<<GH_BLK, 256, 0, stream>>>(gh, bsum_ex, gsc);
  coarse_scatter_kernel<<<NB, 256, 0, stream>>>(src, dst, gsc, ebuf);
  fine_sort_kernel<<<NBUCK, 256, 0, stream>>>(ebuf, gsc, csr, offs);
  gather_kernel<<<(NN * 16 + 255) / 256, 256, 0, stream>>>(
      (const uint4*)hbf, offs, csr, (uint4*)hneighbf);
  gemm_kernel<<<512, 256, 0, stream>>>((const uint4*)hbf, (const uint4*)hneighbf,
                                       (const uint4*)wbf, bias, out);
}

// Round 6
// 226.660 us; speedup vs baseline: 12.8183x; 1.1414x over previous
//
#include <hip/hip_runtime.h>
#include <stdint.h>

#define NN 100000
#define NE 1600000
#define DD 128
#define NTILES ((NN + 127) / 128)   // 782
#define NB 256                      // phase-A blocks
#define CHUNK (NE / NB)             // 6250
#define NBUCK ((NN + 255) / 256)    // 391 coarse buckets (dst>>8)
#define GH_N (NBUCK * NB)           // 100,096
#define GH_BLK (GH_N / 256)         // 391 scan blocks (exact)

typedef __bf16 bf16x8 __attribute__((ext_vector_type(8)));
typedef float f32x4 __attribute__((ext_vector_type(4)));
typedef float f32x2 __attribute__((ext_vector_type(2)));

// round-to-nearest-even fp32 -> bf16, two at a time, packed into a uint
__device__ __forceinline__ unsigned int f2bf2(float a, float b) {
  union { float f; unsigned u; } x, y;
  x.f = a; y.f = b;
  unsigned ua = x.u + (0x7FFFu + ((x.u >> 16) & 1u));
  unsigned ub = y.u + (0x7FFFu + ((y.u >> 16) & 1u));
  return (ua >> 16) | (ub & 0xFFFF0000u);
}

// ---------------- 0. h (fp32) -> h8 (fp8 e4m3), 8 elems/thread --------------
__global__ __launch_bounds__(256) void convert_h8_kernel(const float4* __restrict__ hp,
                                                         uint2* __restrict__ h8) {
  int gid = blockIdx.x * 256 + threadIdx.x;   // NN*DD/8 = 1.6M threads
  float4 a = hp[2 * gid], b = hp[2 * gid + 1];
  int lo = __builtin_amdgcn_cvt_pk_fp8_f32(a.x, a.y, 0, false);
  lo = __builtin_amdgcn_cvt_pk_fp8_f32(a.z, a.w, lo, true);
  int hi = __builtin_amdgcn_cvt_pk_fp8_f32(b.x, b.y, 0, false);
  hi = __builtin_amdgcn_cvt_pk_fp8_f32(b.z, b.w, hi, true);
  h8[gid] = make_uint2((unsigned)lo, (unsigned)hi);
}

// ---------------- A1. coarse histogram (LDS atomics only) -------------------
__global__ __launch_bounds__(256) void coarse_hist_kernel(const int* __restrict__ dst,
                                                          int* __restrict__ gh) {
  __shared__ int lh[NBUCK];
  int t = threadIdx.x, b = blockIdx.x;
  for (int i = t; i < NBUCK; i += 256) lh[i] = 0;
  __syncthreads();
  int e0 = b * CHUNK;
  for (int e = e0 + t; e < e0 + CHUNK; e += 256)
    atomicAdd(&lh[dst[e] >> 8], 1);
  __syncthreads();
  for (int i = t; i < NBUCK; i += 256) gh[i * NB + b] = lh[i];
}

// ---------------- A2. hierarchical exclusive scan of gh ---------------------
__global__ __launch_bounds__(256) void blocksum_kernel(const int* __restrict__ gh,
                                                       int* __restrict__ bsum) {
  __shared__ int s[256];
  int t = threadIdx.x;
  s[t] = gh[blockIdx.x * 256 + t];
  __syncthreads();
  for (int d = 128; d > 0; d >>= 1) {
    if (t < d) s[t] += s[t + d];
    __syncthreads();
  }
  if (t == 0) bsum[blockIdx.x] = s[0];
}

__global__ __launch_bounds__(512) void scanbsum_kernel(const int* __restrict__ bsum,
                                                       int* __restrict__ bsum_ex) {
  __shared__ int s[512];
  int t = threadIdx.x;
  int v = (t < GH_BLK) ? bsum[t] : 0;
  s[t] = v;
  __syncthreads();
  for (int d = 1; d < 512; d <<= 1) {
    int x = (t >= d) ? s[t - d] : 0;
    __syncthreads();
    s[t] += x;
    __syncthreads();
  }
  if (t < GH_BLK) bsum_ex[t] = s[t] - v;
}

__global__ __launch_bounds__(256) void scanfull_kernel(const int* __restrict__ gh,
                                                       const int* __restrict__ bsum_ex,
                                                       int* __restrict__ gsc) {
  __shared__ int s[256];
  int t = threadIdx.x;
  int idx = blockIdx.x * 256 + t;
  int v = gh[idx];
  s[t] = v;
  __syncthreads();
  for (int d = 1; d < 256; d <<= 1) {
    int x = (t >= d) ? s[t - d] : 0;
    __syncthreads();
    s[t] += x;
    __syncthreads();
  }
  gsc[idx] = bsum_ex[blockIdx.x] + s[t] - v;
}

// ---------------- A3. coarse scatter, LDS-staged burst writeback ------------
// Stages all 6250 edges (data + global position) in LDS, then flushes in one
// ordered burst so each 128B ebuf line is touched once per block (kills the
// cross-XCD line ping-pong of incremental scattered writes).
__global__ __launch_bounds__(256) void coarse_scatter_kernel(
    const int* __restrict__ src, const int* __restrict__ dst,
    const int* __restrict__ gsc, unsigned* __restrict__ ebuf) {
  __shared__ int lhpad[512];
  __shared__ int lbase[NBUCK];
  __shared__ int lcur[NBUCK];
  __shared__ int gstart[NBUCK];
  __shared__ unsigned sdata[CHUNK];
  __shared__ int sgpos[CHUNK];
  int t = threadIdx.x, b = blockIdx.x;
  lhpad[t] = 0;
  lhpad[t + 256] = 0;
  __syncthreads();
  int e0 = b * CHUNK;
  for (int e = e0 + t; e < e0 + CHUNK; e += 256)
    atomicAdd(&lhpad[dst[e] >> 8], 1);
  __syncthreads();
  int cnt0 = lhpad[t], cnt1 = lhpad[t + 256];
  for (int d = 1; d < 512; d <<= 1) {
    int x0 = (t >= d) ? lhpad[t - d] : 0;
    int x1 = ((t + 256) >= d) ? lhpad[t + 256 - d] : 0;
    __syncthreads();
    lhpad[t] += x0;
    lhpad[t + 256] += x1;
    __syncthreads();
  }
  if (t < NBUCK) { lbase[t] = lhpad[t] - cnt0; lcur[t] = 0; gstart[t] = gsc[t * NB + b]; }
  int i2 = t + 256;
  if (i2 < NBUCK) { lbase[i2] = lhpad[i2] - cnt1; lcur[i2] = 0; gstart[i2] = gsc[i2 * NB + b]; }
  __syncthreads();
  for (int e = e0 + t; e < e0 + CHUNK; e += 256) {
    int d = dst[e], s = src[e];
    int bk = d >> 8;
    int slot = atomicAdd(&lcur[bk], 1);
    int lp = lbase[bk] + slot;
    sdata[lp] = ((unsigned)(d & 255) << 24) | (unsigned)s;
    sgpos[lp] = gstart[bk] + slot;
  }
  __syncthreads();
  for (int j = t; j < CHUNK; j += 256) ebuf[sgpos[j]] = sdata[j];
}

// ---------------- B. fine sort within bucket -> csr + offs ------------------
__global__ __launch_bounds__(256) void fine_sort_kernel(const unsigned* __restrict__ ebuf,
                                                        const int* __restrict__ gsc,
                                                        int* __restrict__ csr,
                                                        int* __restrict__ offs) {
  __shared__ int hist[256], scn[256], cur[256];
  int t = threadIdx.x, g = blockIdx.x;
  int base = gsc[g * NB];
  int end = (g == NBUCK - 1) ? NE : gsc[(g + 1) * NB];
  hist[t] = 0;
  __syncthreads();
  for (int j = base + t; j < end; j += 256)
    atomicAdd(&hist[ebuf[j] >> 24], 1);
  __syncthreads();
  int v = hist[t];
  scn[t] = v;
  __syncthreads();
  for (int d = 1; d < 256; d <<= 1) {
    int x = (t >= d) ? scn[t - d] : 0;
    __syncthreads();
    scn[t] += x;
    __syncthreads();
  }
  int excl = scn[t] - v;
  int node = g * 256 + t;
  if (node < NN) offs[node] = base + excl;
  if (node == NN - 1) offs[NN] = NE;
  cur[t] = excl;
  __syncthreads();
  for (int j = base + t; j < end; j += 256) {
    unsigned p = ebuf[j];
    int pos = atomicAdd(&cur[p >> 24], 1);
    csr[base + pos] = (int)(p & 0x00FFFFFFu);
  }
}

// ---------------- 4. gather-mean over fp8 h, one node per 8 lanes -----------
// fp8 row = 128 B = 8 lanes x uint4 (16 fp8 each); 8 rows per wave-load.
__device__ __forceinline__ void acc16(float* a, uint4 u) {
  f32x2 p;
  p = __builtin_amdgcn_cvt_pk_f32_fp8(u.x, false); a[0] += p.x;  a[1] += p.y;
  p = __builtin_amdgcn_cvt_pk_f32_fp8(u.x, true);  a[2] += p.x;  a[3] += p.y;
  p = __builtin_amdgcn_cvt_pk_f32_fp8(u.y, false); a[4] += p.x;  a[5] += p.y;
  p = __builtin_amdgcn_cvt_pk_f32_fp8(u.y, true);  a[6] += p.x;  a[7] += p.y;
  p = __builtin_amdgcn_cvt_pk_f32_fp8(u.z, false); a[8] += p.x;  a[9] += p.y;
  p = __builtin_amdgcn_cvt_pk_f32_fp8(u.z, true);  a[10] += p.x; a[11] += p.y;
  p = __builtin_amdgcn_cvt_pk_f32_fp8(u.w, false); a[12] += p.x; a[13] += p.y;
  p = __builtin_amdgcn_cvt_pk_f32_fp8(u.w, true);  a[14] += p.x; a[15] += p.y;
}

__global__ __launch_bounds__(256) void gather_kernel(const uint4* __restrict__ h8,
                                                     const int* __restrict__ offs,
                                                     const int* __restrict__ csr,
                                                     uint4* __restrict__ hneighbf4) {
  int q = (blockIdx.x * 256 + threadIdx.x) >> 3;   // node id
  int l = threadIdx.x & 7;                         // 16B chunk within fp8 row
  if (q >= NN) return;
  int off0 = offs[q], off1 = offs[q + 1];
  float a[16];
#pragma unroll
  for (int i = 0; i < 16; i++) a[i] = 0.f;
  int j = off0;
  for (; j + 4 <= off1; j += 4) {
    int s0 = csr[j], s1 = csr[j + 1], s2 = csr[j + 2], s3 = csr[j + 3];
    uint4 u0 = h8[(size_t)s0 * 8 + l];
    uint4 u1 = h8[(size_t)s1 * 8 + l];
    uint4 u2 = h8[(size_t)s2 * 8 + l];
    uint4 u3 = h8[(size_t)s3 * 8 + l];
    acc16(a, u0); acc16(a, u1); acc16(a, u2); acc16(a, u3);
  }
  for (; j < off1; j++) acc16(a, h8[(size_t)csr[j] * 8 + l]);
  int deg = off1 - off0;
  float sc = (deg > 0) ? (1.0f / (float)deg) : 0.0f;
  uint4 r0, r1;
  r0.x = f2bf2(a[0] * sc, a[1] * sc);   r0.y = f2bf2(a[2] * sc, a[3] * sc);
  r0.z = f2bf2(a[4] * sc, a[5] * sc);   r0.w = f2bf2(a[6] * sc, a[7] * sc);
  r1.x = f2bf2(a[8] * sc, a[9] * sc);   r1.y = f2bf2(a[10] * sc, a[11] * sc);
  r1.z = f2bf2(a[12] * sc, a[13] * sc); r1.w = f2bf2(a[14] * sc, a[15] * sc);
  hneighbf4[(size_t)q * 16 + 2 * l] = r0;
  hneighbf4[(size_t)q * 16 + 2 * l + 1] = r1;
}

// ---------------- staging into fragment-linear LDS --------------------------
// from fp32 row-major (h, W): convert to bf16 during staging
__device__ __forceinline__ void stage_f32(const float* __restrict__ X,
                                          int row0, int nvalid,
                                          uint4* buf, int t) {
#pragma unroll
  for (int i = 0; i < 8; i++) {
    int id = t + (i << 8);     // 0..2047
    int r = id >> 4;           // 0..127
    int c8 = id & 15;          // 0..15
    int row = row0 + r;
    float4 v0 = {0.f, 0.f, 0.f, 0.f}, v1 = {0.f, 0.f, 0.f, 0.f};
    if (row < nvalid) {
      const float4* p = (const float4*)(X + (size_t)row * DD + (c8 << 3));
      v0 = p[0];
      v1 = p[1];
    }
    uint4 q;
    q.x = f2bf2(v0.x, v0.y);
    q.y = f2bf2(v0.z, v0.w);
    q.z = f2bf2(v1.x, v1.y);
    q.w = f2bf2(v1.z, v1.w);
    int rt = r >> 4, m = r & 15, kc = c8 >> 2, quad = c8 & 3;
    buf[(((rt << 2) + kc) << 6) + (quad << 4) + m] = q;
  }
}

// from bf16 row-major (hneigh): pure permuted copy
__device__ __forceinline__ void stage_bf(const uint4* __restrict__ X,
                                         int row0, int nvalid,
                                         uint4* buf, int t) {
#pragma unroll
  for (int i = 0; i < 8; i++) {
    int d = t + (i << 8);
    int rt = d >> 8, kc = (d >> 6) & 3, quad = (d >> 4) & 3, m = d & 15;
    int r = rt * 16 + m, c8 = kc * 4 + quad;
    int row = row0 + r;
    uint4 q = {0u, 0u, 0u, 0u};
    if (row < nvalid) q = X[(size_t)row * 16 + c8];
    buf[d] = q;
  }
}

__device__ __forceinline__ void compute_half(const uint4* sA, const uint4* sW,
                                             f32x4 acc[2][8], int wv, int lane) {
#pragma unroll
  for (int kc = 0; kc < 4; kc++) {
    bf16x8 b[8];
#pragma unroll
    for (int n = 0; n < 8; n++)
      b[n] = *(const bf16x8*)&sW[(((n << 2) + kc) << 6) + lane];
    bf16x8 a0 = *(const bf16x8*)&sA[((((wv * 2 + 0) << 2) + kc) << 6) + lane];
    bf16x8 a1 = *(const bf16x8*)&sA[((((wv * 2 + 1) << 2) + kc) << 6) + lane];
#pragma unroll
    for (int n = 0; n < 8; n++) {
      acc[0][n] = __builtin_amdgcn_mfma_f32_16x16x32_bf16(a0, b[n], acc[0][n], 0, 0, 0);
      acc[1][n] = __builtin_amdgcn_mfma_f32_16x16x32_bf16(a1, b[n], acc[1][n], 0, 0, 0);
    }
  }
}

// ---------------- 5. fused: out = h@Ws^T + hneigh@Wn^T + b ------------------
__global__ __launch_bounds__(256) void gemm_kernel(
    const float* __restrict__ h, const uint4* __restrict__ hneighbf,
    const float* __restrict__ Wself, const float* __restrict__ Wneigh,
    const float* __restrict__ bias, float* __restrict__ out) {
  __shared__ uint4 sA[2048];
  __shared__ uint4 sW[2048];
  int t = threadIdx.x;
  int wv = t >> 6;
  int lane = t & 63;
  int row0 = blockIdx.x * 128;

  f32x4 acc[2][8];
#pragma unroll
  for (int i = 0; i < 2; i++)
#pragma unroll
    for (int n = 0; n < 8; n++) acc[i][n] = f32x4{0.f, 0.f, 0.f, 0.f};

  // half 1: h @ Wself^T (both staged fp32 -> bf16)
  stage_f32(h, row0, NN, sA, t);
  stage_f32(Wself, 0, 128, sW, t);
  __syncthreads();
  compute_half(sA, sW, acc, wv, lane);
  __syncthreads();

  // half 2: hneigh @ Wneigh^T
  stage_bf(hneighbf, row0, NN, sA, t);
  stage_f32(Wneigh, 0, 128, sW, t);
  __syncthreads();
  compute_half(sA, sW, acc, wv, lane);

  // epilogue: + bias (C/D layout: col=lane&15, row=(lane>>4)*4+reg)
  int col = lane & 15, rq = lane >> 4;
  float bv[8];
#pragma unroll
  for (int n = 0; n < 8; n++) bv[n] = bias[n * 16 + col];
#pragma unroll
  for (int rt = 0; rt < 2; rt++) {
    int rb = row0 + (wv * 2 + rt) * 16 + rq * 4;
#pragma unroll
    for (int r = 0; r < 4; r++) {
      int row = rb + r;
      if (row < NN) {
        float* op = out + (size_t)row * DD + col;
#pragma unroll
        for (int n = 0; n < 8; n++) op[n * 16] = acc[rt][n][r] + bv[n];
      }
    }
  }
}

extern "C" void kernel_launch(void* const* d_in, const int* in_sizes, int n_in,
                              void* d_out, int out_size, void* d_ws, size_t ws_size,
                              hipStream_t stream) {
  const float* h      = (const float*)d_in[0];
  const int*   src    = (const int*)d_in[1];
  const int*   dst    = (const int*)d_in[2];
  const float* Wself  = (const float*)d_in[3];
  const float* Wneigh = (const float*)d_in[4];
  const float* bias   = (const float*)d_in[5];
  float* out = (float*)d_out;

  // workspace layout (bytes); ebuf aliases hneigh region (dead until gather).
  // Peak footprint: ~46.0 MB.
  char* ws = (char*)d_ws;
  unsigned* h8       = (unsigned*)ws;                     // 12,800,000
  unsigned* hneighbf = (unsigned*)(ws + 12800000);        // 25,600,000
  unsigned* ebuf     = (unsigned*)(ws + 12800000);        //  6,400,000 (alias)
  int*      csr      = (int*)(ws + 38400000);             //  6,400,000
  int*      gh       = (int*)(ws + 44800000);             //    400,384
  int*      gsc      = (int*)(ws + 45200384);             //    400,384
  int*      bsum     = (int*)(ws + 45600768);             //      1,568
  int*      bsum_ex  = (int*)(ws + 45602336);             //      1,568
  int*      offs     = (int*)(ws + 45603904);             //    400,016

  convert_h8_kernel<<<6250, 256, 0, stream>>>((const float4*)h, (uint2*)h8);
  coarse_hist_kernel<<<NB, 256, 0, stream>>>(dst, gh);
  blocksum_kernel<<<GH_BLK, 256, 0, stream>>>(gh, bsum);
  scanbsum_kernel<<<1, 512, 0, stream>>>(bsum, bsum_ex);
  scanfull_kernel<<<GH_BLK, 256, 0, stream>>>(gh, bsum_ex, gsc);
  coarse_scatter_kernel<<<NB, 256, 0, stream>>>(src, dst, gsc, ebuf);
  fine_sort_kernel<<<NBUCK, 256, 0, stream>>>(ebuf, gsc, csr, offs);
  gather_kernel<<<(NN * 8 + 255) / 256, 256, 0, stream>>>(
      (const uint4*)h8, offs, csr, (uint4*)hneighbf);
  gemm_kernel<<<NTILES, 256, 0, stream>>>(h, (const uint4*)hneighbf,
                                          Wself, Wneigh, bias, out);
}